// Round 2
// baseline (432.320 us; speedup 1.0000x reference)
//
#include <hip/hip_runtime.h>

typedef _Float16 f16;
typedef f16 f16x8 __attribute__((ext_vector_type(8)));
typedef f16 f16x4 __attribute__((ext_vector_type(4)));
typedef __fp16 h16x2 __attribute__((ext_vector_type(2)));   // cvt_pkrtz native type
typedef float f32x4 __attribute__((ext_vector_type(4)));
typedef float f32x2 __attribute__((ext_vector_type(2)));

#define MFMA16(A, B, C) __builtin_amdgcn_mfma_f32_16x16x32_f16((A), (B), (C), 0, 0, 0)

// Barrier WITHOUT vmcnt drain: only LDS (lgkmcnt) must be visible across it.
// (R6: LDS flag sync is WORSE than s_barrier; __syncthreads would drain vmcnt
// and serialize the in-flight x prefetch.)
#define LDS_BARRIER() asm volatile("s_waitcnt lgkmcnt(0)\n\ts_barrier" ::: "memory")

__device__ __forceinline__ float E2(float x) {   // 2^x
#if __has_builtin(__builtin_amdgcn_exp2f)
  return __builtin_amdgcn_exp2f(x);
#else
  return __expf(x * 0.69314718056f);
#endif
}

__device__ __forceinline__ f16x8 cvt8(float4 a, float4 b) {
  union { h16x2 h[4]; f16x8 v; } u;
  u.h[0] = __builtin_amdgcn_cvt_pkrtz(a.x, a.y);
  u.h[1] = __builtin_amdgcn_cvt_pkrtz(a.z, a.w);
  u.h[2] = __builtin_amdgcn_cvt_pkrtz(b.x, b.y);
  u.h[3] = __builtin_amdgcn_cvt_pkrtz(b.z, b.w);
  return u.v;
}

// scaled weight-load convert (init-time only)
__device__ __forceinline__ f16x8 cvt8s(const float* p, float s) {
  float4 a = *(const float4*)p;
  float4 b = *(const float4*)(p + 4);
  union { h16x2 h[4]; f16x8 v; } u;
  u.h[0] = __builtin_amdgcn_cvt_pkrtz(a.x * s, a.y * s);
  u.h[1] = __builtin_amdgcn_cvt_pkrtz(a.z * s, a.w * s);
  u.h[2] = __builtin_amdgcn_cvt_pkrtz(b.x * s, b.y * s);
  u.h[3] = __builtin_amdgcn_cvt_pkrtz(b.z * s, b.w * s);
  return u.v;
}

__device__ __forceinline__ f16x4 pack4(f32x2 a, f32x2 b) {
  union { h16x2 h2[2]; f16x4 v; } u;
  u.h2[0] = __builtin_amdgcn_cvt_pkrtz(a[0], a[1]);
  u.h2[1] = __builtin_amdgcn_cvt_pkrtz(b[0], b[1]);
  return u.v;
}

// Packed gate math for a pair of h-rows.  float2 ops -> v_pk_*_f32.
// R7/R8: gate pre-scales are FOLDED INTO THE WEIGHTS/BIASES at load time:
//   aR,aZ arrive pre-multiplied by -log2(e)    -> ea = 2^aR = e^{-pre}
//   aXN,aHN arrive pre-multiplied by -2log2(e) -> my = aXN + r*aHN = -2log2e*y
// Removes 3 pk-muls and puts exp2 directly after the MFMA result.
// sigmoid pair shares one rcp; tanh(y) = (1-c)*rcp(1+c), c = 2^(-2log2e*y).
// Verified R7: absmax 0.0039 (unchanged).
__device__ __forceinline__ void gates_pair(f32x2 aR, f32x2 aZ, f32x2 aXN,
                                           f32x2 aHN, f32x2& hs) {
  f32x2 ea, eb;
  ea[0] = E2(aR[0]); ea[1] = E2(aR[1]);
  eb[0] = E2(aZ[0]); eb[1] = E2(aZ[1]);
  f32x2 pa = ea + 1.0f;
  f32x2 pb = eb + 1.0f;
  f32x2 prod = pa * pb;
  f32x2 inv;
  inv[0] = __builtin_amdgcn_rcpf(prod[0]);
  inv[1] = __builtin_amdgcn_rcpf(prod[1]);
  f32x2 rg = pb * inv;                 // sigmoid(r pre-act)
  f32x2 zg = pa * inv;                 // sigmoid(z pre-act)
  f32x2 my = aXN + rg * aHN;           // = -2log2e * (xn + r*hn)
  f32x2 c;
  c[0] = E2(my[0]); c[1] = E2(my[1]);
  f32x2 num = 1.0f - c;
  f32x2 den = 1.0f + c;
  f32x2 rin;
  rin[0] = __builtin_amdgcn_rcpf(den[0]);
  rin[1] = __builtin_amdgcn_rcpf(den[1]);
  f32x2 ng = num * rin;                // tanh(y)
  hs = zg * (hs - ng) + ng;
}

// B=4096, T=128, D=32, H=64.
//
// R8 structure: back to the R5 8-wave split-role design (R7's merged-role
// 4-wave WG FAILED: in-order issue means intra-wave ILP cannot replace
// cross-wave latency hiding; 1 wave/SIMD exposed every dep stall).
// NEW in R8: the WG handles 8 REAL batches (MFMA cols 8-15 are discarded
// duplicates) and the grid doubles to 512 WGs -> 2 independent WGs per CU,
// 4 waves/SIMD.  Per-wave instruction count is batch-width-independent, so
// the extra issue lands in what were stall cycles: two WGs have independent
// barriers and skewed chains, hiding each other's ds_read/exp2/MFMA latency.
// Batch columns are fully independent (MFMA mixes over K=rows only, gate
// math is lane-local per column), so garbage cols never touch real ones.
//
// Waves 0-3 (group A): layer 0, step t.  Waves 4-7 (group B): layer 1, t-1.
// Time loop unrolled x2 (parity/prefetch slots compile-time; R4:
// runtime-indexed arrays -> scratch).  One LDS-only s_barrier per step.
// H LDS layout: h[k] for batch b at f16 offset ((k>>3)*16+b)*8 + (k&7)
//   -> B-frag for lane L, kfrag f = stride-1 ds_read_b128 at f*1024 + L*16.
__launch_bounds__(512, 4)
__global__ void gru_fused(const float* __restrict__ x,
                          const float* __restrict__ Wih0, const float* __restrict__ Whh0,
                          const float* __restrict__ bih0, const float* __restrict__ bhh0,
                          const float* __restrict__ Wih1, const float* __restrict__ Whh1,
                          const float* __restrict__ bih1, const float* __restrict__ bhh1,
                          const float* __restrict__ fcw, const float* __restrict__ fcb,
                          float* __restrict__ out) {
  __shared__ f16 H0[2][1024];
  __shared__ f16 H1[2][1024];
  __shared__ float red[4][16];

  const int tid = threadIdx.x;
  const int wave = tid >> 6;
  const int lane = tid & 63;
  const int l15 = lane & 15;
  const int q = lane >> 4;
  const int wa = wave & 3;
  const bool isB = wave >= 4;
  const int b0 = blockIdx.x * 8;            // 8 real batches per WG (R8)

  for (int i = tid; i < 2048; i += 512) {
    ((f16*)H0)[i] = (f16)0.0f;
    ((f16*)H1)[i] = (f16)0.0f;
  }

  const float SRZ = -1.44269504f;     // -log2(e)      folded into r,z rows
  const float SN  = -2.88539008f;     // -2*log2(e)    folded into n rows

  // ---- register-resident weight A-fragments: A[m=l15][k = kf*32 + q*8 + j]
  f16x8 wAx[3];          // layer0 Wih (K=32)       — group A only
  f16x8 wAh[3][2];       // layer0 Whh (K=64)       — group A only
  f16x8 wBx[3][2];       // layer1 Wih (K=64)       — group B only
  f16x8 wBh[3][2];       // layer1 Whh (K=64)       — group B only
  f32x4 bR, bZ, bXN, bHN;
  float fw[4] = {0.f, 0.f, 0.f, 0.f};

  if (!isB) {
#pragma unroll
    for (int g = 0; g < 3; ++g) {
      const float s = (g == 2) ? SN : SRZ;
      const int row = g * 64 + 16 * wa + l15;
      wAx[g] = cvt8s(Wih0 + row * 32 + q * 8, s);
#pragma unroll
      for (int kf = 0; kf < 2; ++kf) {
        wAh[g][kf] = cvt8s(Whh0 + row * 64 + kf * 32 + q * 8, s);
      }
    }
#pragma unroll
    for (int r = 0; r < 4; ++r) {
      const int o = 16 * wa + 4 * q + r;
      bR[r]  = SRZ * (bih0[o] + bhh0[o]);
      bZ[r]  = SRZ * (bih0[64 + o] + bhh0[64 + o]);
      bXN[r] = SN * bih0[128 + o];
      bHN[r] = SN * bhh0[128 + o];
    }
  } else {
#pragma unroll
    for (int g = 0; g < 3; ++g) {
      const float s = (g == 2) ? SN : SRZ;
      const int row = g * 64 + 16 * wa + l15;
#pragma unroll
      for (int kf = 0; kf < 2; ++kf) {
        wBx[g][kf] = cvt8s(Wih1 + row * 64 + kf * 32 + q * 8, s);
        wBh[g][kf] = cvt8s(Whh1 + row * 64 + kf * 32 + q * 8, s);
      }
    }
#pragma unroll
    for (int r = 0; r < 4; ++r) {
      const int o = 16 * wa + 4 * q + r;
      bR[r]  = SRZ * (bih1[o] + bhh1[o]);
      bZ[r]  = SRZ * (bih1[64 + o] + bhh1[64 + o]);
      bXN[r] = SN * bih1[128 + o];
      bHN[r] = SN * bhh1[128 + o];
      fw[r] = fcw[o];
    }
  }
  const float fcb0 = fcb[0];

  f32x2 hs01 = {0.f, 0.f}, hs23 = {0.f, 0.f};  // this lane's 4 h rows (own layer)

  const int wk0 = 16 * wa + 4 * q;                          // this lane's 4 h-row indices
  const int widx = ((wk0 >> 3) * 16 + l15) * 8 + (wk0 & 7); // f16 offset of its b64 store

  // layer-0 step: read H0r, consume x frag, write H0w
  auto stepA = [&](const f16* H0r, f16* H0w, float4 xav, float4 xbv) {
    const f16x8 xf = cvt8(xav, xbv);
    const f16x8 h0f0 = *(const f16x8*)&H0r[lane * 8];
    const f16x8 h0f1 = *(const f16x8*)&H0r[512 + lane * 8];
    f32x4 aR  = MFMA16(wAx[0], xf, bR);
    f32x4 aZ  = MFMA16(wAx[1], xf, bZ);
    f32x4 aXN = MFMA16(wAx[2], xf, bXN);
    f32x4 aHN = MFMA16(wAh[2][0], h0f0, bHN);
    aR  = MFMA16(wAh[0][0], h0f0, aR);
    aZ  = MFMA16(wAh[1][0], h0f0, aZ);
    aR  = MFMA16(wAh[0][1], h0f1, aR);
    aZ  = MFMA16(wAh[1][1], h0f1, aZ);
    aHN = MFMA16(wAh[2][1], h0f1, aHN);
    gates_pair(f32x2{aR[0], aR[1]}, f32x2{aZ[0], aZ[1]},
               f32x2{aXN[0], aXN[1]}, f32x2{aHN[0], aHN[1]}, hs01);
    gates_pair(f32x2{aR[2], aR[3]}, f32x2{aZ[2], aZ[3]},
               f32x2{aXN[2], aXN[3]}, f32x2{aHN[2], aHN[3]}, hs23);
    *(f16x4*)&H0w[widx] = pack4(hs01, hs23);
  };

  // layer-1 step: read h0 from H0r, own state from H1r, write H1w
  auto stepB = [&](const f16* H0r, const f16* H1r, f16* H1w) {
    const f16x8 g0 = *(const f16x8*)&H0r[lane * 8];
    const f16x8 g1 = *(const f16x8*)&H0r[512 + lane * 8];
    const f16x8 h1f0 = *(const f16x8*)&H1r[lane * 8];
    const f16x8 h1f1 = *(const f16x8*)&H1r[512 + lane * 8];
    f32x4 aR  = MFMA16(wBx[0][0], g0, bR);
    f32x4 aZ  = MFMA16(wBx[1][0], g0, bZ);
    f32x4 aXN = MFMA16(wBx[2][0], g0, bXN);
    aR  = MFMA16(wBx[0][1], g1, aR);
    aZ  = MFMA16(wBx[1][1], g1, aZ);
    aXN = MFMA16(wBx[2][1], g1, aXN);
    f32x4 aHN = MFMA16(wBh[2][0], h1f0, bHN);
    aR  = MFMA16(wBh[0][0], h1f0, aR);
    aZ  = MFMA16(wBh[1][0], h1f0, aZ);
    aR  = MFMA16(wBh[0][1], h1f1, aR);
    aZ  = MFMA16(wBh[1][1], h1f1, aZ);
    aHN = MFMA16(wBh[2][1], h1f1, aHN);
    gates_pair(f32x2{aR[0], aR[1]}, f32x2{aZ[0], aZ[1]},
               f32x2{aXN[0], aXN[1]}, f32x2{aHN[0], aHN[1]}, hs01);
    gates_pair(f32x2{aR[2], aR[3]}, f32x2{aZ[2], aZ[3]},
               f32x2{aXN[2], aXN[3]}, f32x2{aHN[2], aHN[3]}, hs23);
    *(f16x4*)&H1w[widx] = pack4(hs01, hs23);
  };

  __syncthreads();

  // x B-frag source (group A only): lane (l15,q) reads x[bb][t][q*8..q*8+7].
  // bb clamped to 4095: cols l15>=8 are discarded duplicates, and the last
  // WG (b0=4088) would otherwise read past the end of x.
  const int bb = min(b0 + l15, 4095);
  const float* xbase = x + (size_t)bb * 4096 + q * 8;
  float4 xa0, xb0, xa1, xb1;
  if (!isB) {
    xa0 = *(const float4*)xbase;
    xb0 = *(const float4*)(xbase + 4);
    xa1 = *(const float4*)(xbase + 32);
    xb1 = *(const float4*)(xbase + 36);
  }

  for (int t = 0; t < 128; t += 2) {
    // ---- pipeline iteration t (parity 0): A step t, B step t-1
    if (!isB) {
      const float4 cxa = xa0, cxb = xb0;
      if (t + 2 < 128) {
        const float* xp = xbase + (t + 2) * 32;
        xa0 = *(const float4*)xp;
        xb0 = *(const float4*)(xp + 4);
      }
      stepA(H0[0], H0[1], cxa, cxb);
    } else if (t > 0) {
      stepB(H0[0], H1[0], H1[1]);
    }
    LDS_BARRIER();

    // ---- pipeline iteration t+1 (parity 1): A step t+1, B step t
    if (!isB) {
      const float4 cxa = xa1, cxb = xb1;
      if (t + 3 < 128) {
        const float* xp = xbase + (t + 3) * 32;
        xa1 = *(const float4*)xp;
        xb1 = *(const float4*)(xp + 4);
      }
      stepA(H0[1], H0[0], cxa, cxb);
    } else {
      stepB(H0[1], H1[1], H1[0]);
    }
    LDS_BARRIER();
  }
  // ---- pipeline iteration t=128 (parity 0): B step 127 only
  if (isB) stepB(H0[0], H1[0], H1[1]);

  // ---- fc: out[b] = sum_i h1[i]*fcw[i] + fcb   (group B holds h1(127))
  if (isB) {
    float partial = fw[0] * hs01[0] + fw[1] * hs01[1] + fw[2] * hs23[0] + fw[3] * hs23[1];
    partial += __shfl_down(partial, 16, 64);
    partial += __shfl_down(partial, 32, 64);
    if (lane < 16) red[wa][l15] = partial;
  }
  __syncthreads();
  if (tid < 8) out[b0 + tid] = red[0][tid] + red[1][tid] + red[2][tid] + red[3][tid] + fcb0;
}

extern "C" void kernel_launch(void* const* d_in, const int* in_sizes, int n_in,
                              void* d_out, int out_size, void* d_ws, size_t ws_size,
                              hipStream_t stream) {
  (void)in_sizes; (void)n_in; (void)out_size; (void)d_ws; (void)ws_size;
  const float* x    = (const float*)d_in[0];
  const float* Wih0 = (const float*)d_in[1];
  const float* Whh0 = (const float*)d_in[2];
  const float* bih0 = (const float*)d_in[3];
  const float* bhh0 = (const float*)d_in[4];
  const float* Wih1 = (const float*)d_in[5];
  const float* Whh1 = (const float*)d_in[6];
  const float* bih1 = (const float*)d_in[7];
  const float* bhh1 = (const float*)d_in[8];
  const float* fcw  = (const float*)d_in[9];
  const float* fcb  = (const float*)d_in[10];
  float* out = (float*)d_out;

  gru_fused<<<512, 512, 0, stream>>>(x, Wih0, Whh0, bih0, bhh0,
                                     Wih1, Whh1, bih1, bhh1, fcw, fcb, out);
}

// Round 3
// 241.432 us; speedup vs baseline: 1.7906x; 1.7906x over previous
//
#include <hip/hip_runtime.h>

typedef _Float16 f16;
typedef f16 f16x8 __attribute__((ext_vector_type(8)));
typedef f16 f16x4 __attribute__((ext_vector_type(4)));
typedef __fp16 h16x2 __attribute__((ext_vector_type(2)));   // cvt_pkrtz native type
typedef float f32x4 __attribute__((ext_vector_type(4)));
typedef float f32x2 __attribute__((ext_vector_type(2)));

#define MFMA16(A, B, C) __builtin_amdgcn_mfma_f32_16x16x32_f16((A), (B), (C), 0, 0, 0)

// Barrier WITHOUT vmcnt drain: only LDS (lgkmcnt) must be visible across it.
// (R6: LDS flag sync is WORSE than s_barrier; __syncthreads would drain vmcnt
// and serialize the in-flight x prefetch.)
#define LDS_BARRIER() asm volatile("s_waitcnt lgkmcnt(0)\n\ts_barrier" ::: "memory")

__device__ __forceinline__ float E2(float x) {   // 2^x
#if __has_builtin(__builtin_amdgcn_exp2f)
  return __builtin_amdgcn_exp2f(x);
#else
  return __expf(x * 0.69314718056f);
#endif
}

__device__ __forceinline__ f16x8 cvt8(float4 a, float4 b) {
  union { h16x2 h[4]; f16x8 v; } u;
  u.h[0] = __builtin_amdgcn_cvt_pkrtz(a.x, a.y);
  u.h[1] = __builtin_amdgcn_cvt_pkrtz(a.z, a.w);
  u.h[2] = __builtin_amdgcn_cvt_pkrtz(b.x, b.y);
  u.h[3] = __builtin_amdgcn_cvt_pkrtz(b.z, b.w);
  return u.v;
}

// scaled weight-load convert (init-time only)
__device__ __forceinline__ f16x8 cvt8s(const float* p, float s) {
  float4 a = *(const float4*)p;
  float4 b = *(const float4*)(p + 4);
  union { h16x2 h[4]; f16x8 v; } u;
  u.h[0] = __builtin_amdgcn_cvt_pkrtz(a.x * s, a.y * s);
  u.h[1] = __builtin_amdgcn_cvt_pkrtz(a.z * s, a.w * s);
  u.h[2] = __builtin_amdgcn_cvt_pkrtz(b.x * s, b.y * s);
  u.h[3] = __builtin_amdgcn_cvt_pkrtz(b.z * s, b.w * s);
  return u.v;
}

__device__ __forceinline__ f16x4 pack4(f32x2 a, f32x2 b) {
  union { h16x2 h2[2]; f16x4 v; } u;
  u.h2[0] = __builtin_amdgcn_cvt_pkrtz(a[0], a[1]);
  u.h2[1] = __builtin_amdgcn_cvt_pkrtz(b[0], b[1]);
  return u.v;
}

// Packed gate math for a pair of h-rows.  float2 ops -> v_pk_*_f32.
// R7/R8: gate pre-scales are FOLDED INTO THE WEIGHTS/BIASES at load time:
//   aR,aZ arrive pre-multiplied by -log2(e)    -> ea = 2^aR = e^{-pre}
//   aXN,aHN arrive pre-multiplied by -2log2(e) -> my = aXN + r*aHN = -2log2e*y
// Removes 3 pk-muls and puts exp2 directly after the MFMA result.
// sigmoid pair shares one rcp; tanh(y) = (1-c)*rcp(1+c), c = 2^(-2log2e*y).
// Verified R7: absmax 0.0039 (unchanged).
__device__ __forceinline__ void gates_pair(f32x2 aR, f32x2 aZ, f32x2 aXN,
                                           f32x2 aHN, f32x2& hs) {
  f32x2 ea, eb;
  ea[0] = E2(aR[0]); ea[1] = E2(aR[1]);
  eb[0] = E2(aZ[0]); eb[1] = E2(aZ[1]);
  f32x2 pa = ea + 1.0f;
  f32x2 pb = eb + 1.0f;
  f32x2 prod = pa * pb;
  f32x2 inv;
  inv[0] = __builtin_amdgcn_rcpf(prod[0]);
  inv[1] = __builtin_amdgcn_rcpf(prod[1]);
  f32x2 rg = pb * inv;                 // sigmoid(r pre-act)
  f32x2 zg = pa * inv;                 // sigmoid(z pre-act)
  f32x2 my = aXN + rg * aHN;           // = -2log2e * (xn + r*hn)
  f32x2 c;
  c[0] = E2(my[0]); c[1] = E2(my[1]);
  f32x2 num = 1.0f - c;
  f32x2 den = 1.0f + c;
  f32x2 rin;
  rin[0] = __builtin_amdgcn_rcpf(den[0]);
  rin[1] = __builtin_amdgcn_rcpf(den[1]);
  f32x2 ng = num * rin;                // tanh(y)
  hs = zg * (hs - ng) + ng;
}

// B=4096, T=128, D=32, H=64.
//
// R9 = R8 structure (8 real batches / WG, 512 WGs -> 2 independent WGs per
// CU, 4 waves/SIMD) but WITHOUT R8's launch_bounds(512,4) blunder.  R8's
// counters: occupancy did double (46%) proving co-residency, but the
// (512,4) bound made the allocator squeeze 84->64 VGPR and SPILL the
// register-resident weights (WRITE_SIZE 16KB -> 65MB) — it A/B-tested
// "spill the weights", not "double occupancy".  84 VGPR x 4 waves = 336
// <= 512/SIMD, so (512,2) already permits 2 WGs/CU; only the grid change
// was ever needed.
//
// Rationale: per-wave instruction count is batch-width-independent (same
// MFMAs/gate VALU regardless of how many of the 16 columns are real), so
// halving batches/WG and doubling the grid doubles issued work per CU —
// landing in what are currently stall cycles.  Two WGs have independent
// barriers and skewed chains, hiding each other's ds_read/exp2/MFMA
// latency.  Batch columns are fully independent (MFMA mixes over K=rows
// only; gate math is lane-local per column), so duplicate cols are inert.
//
// Waves 0-3 (group A): layer 0, step t.  Waves 4-7 (group B): layer 1, t-1.
// Time loop unrolled x2 (parity/prefetch slots compile-time; R4:
// runtime-indexed arrays -> scratch).  One LDS-only s_barrier per step.
// H LDS layout: h[k] for batch b at f16 offset ((k>>3)*16+b)*8 + (k&7)
//   -> B-frag for lane L, kfrag f = stride-1 ds_read_b128 at f*1024 + L*16.
__launch_bounds__(512, 2)
__global__ void gru_fused(const float* __restrict__ x,
                          const float* __restrict__ Wih0, const float* __restrict__ Whh0,
                          const float* __restrict__ bih0, const float* __restrict__ bhh0,
                          const float* __restrict__ Wih1, const float* __restrict__ Whh1,
                          const float* __restrict__ bih1, const float* __restrict__ bhh1,
                          const float* __restrict__ fcw, const float* __restrict__ fcb,
                          float* __restrict__ out) {
  __shared__ f16 H0[2][1024];
  __shared__ f16 H1[2][1024];
  __shared__ float red[4][16];

  const int tid = threadIdx.x;
  const int wave = tid >> 6;
  const int lane = tid & 63;
  const int l15 = lane & 15;
  const int q = lane >> 4;
  const int wa = wave & 3;
  const bool isB = wave >= 4;
  const int b0 = blockIdx.x * 8;            // 8 real batches per WG

  for (int i = tid; i < 2048; i += 512) {
    ((f16*)H0)[i] = (f16)0.0f;
    ((f16*)H1)[i] = (f16)0.0f;
  }

  const float SRZ = -1.44269504f;     // -log2(e)      folded into r,z rows
  const float SN  = -2.88539008f;     // -2*log2(e)    folded into n rows

  // ---- register-resident weight A-fragments: A[m=l15][k = kf*32 + q*8 + j]
  f16x8 wAx[3];          // layer0 Wih (K=32)       — group A only
  f16x8 wAh[3][2];       // layer0 Whh (K=64)       — group A only
  f16x8 wBx[3][2];       // layer1 Wih (K=64)       — group B only
  f16x8 wBh[3][2];       // layer1 Whh (K=64)       — group B only
  f32x4 bR, bZ, bXN, bHN;
  float fw[4] = {0.f, 0.f, 0.f, 0.f};

  if (!isB) {
#pragma unroll
    for (int g = 0; g < 3; ++g) {
      const float s = (g == 2) ? SN : SRZ;
      const int row = g * 64 + 16 * wa + l15;
      wAx[g] = cvt8s(Wih0 + row * 32 + q * 8, s);
#pragma unroll
      for (int kf = 0; kf < 2; ++kf) {
        wAh[g][kf] = cvt8s(Whh0 + row * 64 + kf * 32 + q * 8, s);
      }
    }
#pragma unroll
    for (int r = 0; r < 4; ++r) {
      const int o = 16 * wa + 4 * q + r;
      bR[r]  = SRZ * (bih0[o] + bhh0[o]);
      bZ[r]  = SRZ * (bih0[64 + o] + bhh0[64 + o]);
      bXN[r] = SN * bih0[128 + o];
      bHN[r] = SN * bhh0[128 + o];
    }
  } else {
#pragma unroll
    for (int g = 0; g < 3; ++g) {
      const float s = (g == 2) ? SN : SRZ;
      const int row = g * 64 + 16 * wa + l15;
#pragma unroll
      for (int kf = 0; kf < 2; ++kf) {
        wBx[g][kf] = cvt8s(Wih1 + row * 64 + kf * 32 + q * 8, s);
        wBh[g][kf] = cvt8s(Whh1 + row * 64 + kf * 32 + q * 8, s);
      }
    }
#pragma unroll
    for (int r = 0; r < 4; ++r) {
      const int o = 16 * wa + 4 * q + r;
      bR[r]  = SRZ * (bih1[o] + bhh1[o]);
      bZ[r]  = SRZ * (bih1[64 + o] + bhh1[64 + o]);
      bXN[r] = SN * bih1[128 + o];
      bHN[r] = SN * bhh1[128 + o];
      fw[r] = fcw[o];
    }
  }
  const float fcb0 = fcb[0];

  f32x2 hs01 = {0.f, 0.f}, hs23 = {0.f, 0.f};  // this lane's 4 h rows (own layer)

  const int wk0 = 16 * wa + 4 * q;                          // this lane's 4 h-row indices
  const int widx = ((wk0 >> 3) * 16 + l15) * 8 + (wk0 & 7); // f16 offset of its b64 store

  // layer-0 step: read H0r, consume x frag, write H0w
  auto stepA = [&](const f16* H0r, f16* H0w, float4 xav, float4 xbv) {
    const f16x8 xf = cvt8(xav, xbv);
    const f16x8 h0f0 = *(const f16x8*)&H0r[lane * 8];
    const f16x8 h0f1 = *(const f16x8*)&H0r[512 + lane * 8];
    f32x4 aR  = MFMA16(wAx[0], xf, bR);
    f32x4 aZ  = MFMA16(wAx[1], xf, bZ);
    f32x4 aXN = MFMA16(wAx[2], xf, bXN);
    f32x4 aHN = MFMA16(wAh[2][0], h0f0, bHN);
    aR  = MFMA16(wAh[0][0], h0f0, aR);
    aZ  = MFMA16(wAh[1][0], h0f0, aZ);
    aR  = MFMA16(wAh[0][1], h0f1, aR);
    aZ  = MFMA16(wAh[1][1], h0f1, aZ);
    aHN = MFMA16(wAh[2][1], h0f1, aHN);
    gates_pair(f32x2{aR[0], aR[1]}, f32x2{aZ[0], aZ[1]},
               f32x2{aXN[0], aXN[1]}, f32x2{aHN[0], aHN[1]}, hs01);
    gates_pair(f32x2{aR[2], aR[3]}, f32x2{aZ[2], aZ[3]},
               f32x2{aXN[2], aXN[3]}, f32x2{aHN[2], aHN[3]}, hs23);
    *(f16x4*)&H0w[widx] = pack4(hs01, hs23);
  };

  // layer-1 step: read h0 from H0r, own state from H1r, write H1w
  auto stepB = [&](const f16* H0r, const f16* H1r, f16* H1w) {
    const f16x8 g0 = *(const f16x8*)&H0r[lane * 8];
    const f16x8 g1 = *(const f16x8*)&H0r[512 + lane * 8];
    const f16x8 h1f0 = *(const f16x8*)&H1r[lane * 8];
    const f16x8 h1f1 = *(const f16x8*)&H1r[512 + lane * 8];
    f32x4 aR  = MFMA16(wBx[0][0], g0, bR);
    f32x4 aZ  = MFMA16(wBx[1][0], g0, bZ);
    f32x4 aXN = MFMA16(wBx[2][0], g0, bXN);
    aR  = MFMA16(wBx[0][1], g1, aR);
    aZ  = MFMA16(wBx[1][1], g1, aZ);
    aXN = MFMA16(wBx[2][1], g1, aXN);
    f32x4 aHN = MFMA16(wBh[2][0], h1f0, bHN);
    aR  = MFMA16(wBh[0][0], h1f0, aR);
    aZ  = MFMA16(wBh[1][0], h1f0, aZ);
    aR  = MFMA16(wBh[0][1], h1f1, aR);
    aZ  = MFMA16(wBh[1][1], h1f1, aZ);
    aHN = MFMA16(wBh[2][1], h1f1, aHN);
    gates_pair(f32x2{aR[0], aR[1]}, f32x2{aZ[0], aZ[1]},
               f32x2{aXN[0], aXN[1]}, f32x2{aHN[0], aHN[1]}, hs01);
    gates_pair(f32x2{aR[2], aR[3]}, f32x2{aZ[2], aZ[3]},
               f32x2{aXN[2], aXN[3]}, f32x2{aHN[2], aHN[3]}, hs23);
    *(f16x4*)&H1w[widx] = pack4(hs01, hs23);
  };

  __syncthreads();

  // x B-frag source (group A only): lane (l15,q) reads x[bb][t][q*8..q*8+7].
  // Duplicate cols (l15>=8) clamp to the WG's own last row b0+7 — same cache
  // lines lane 7 already fetches (R8 clamped to global 4095: pointless far
  // fetch).
  const int bb = b0 + min(l15, 7);
  const float* xbase = x + (size_t)bb * 4096 + q * 8;
  float4 xa0, xb0, xa1, xb1;
  if (!isB) {
    xa0 = *(const float4*)xbase;
    xb0 = *(const float4*)(xbase + 4);
    xa1 = *(const float4*)(xbase + 32);
    xb1 = *(const float4*)(xbase + 36);
  }

  for (int t = 0; t < 128; t += 2) {
    // ---- pipeline iteration t (parity 0): A step t, B step t-1
    if (!isB) {
      const float4 cxa = xa0, cxb = xb0;
      if (t + 2 < 128) {
        const float* xp = xbase + (t + 2) * 32;
        xa0 = *(const float4*)xp;
        xb0 = *(const float4*)(xp + 4);
      }
      stepA(H0[0], H0[1], cxa, cxb);
    } else if (t > 0) {
      stepB(H0[0], H1[0], H1[1]);
    }
    LDS_BARRIER();

    // ---- pipeline iteration t+1 (parity 1): A step t+1, B step t
    if (!isB) {
      const float4 cxa = xa1, cxb = xb1;
      if (t + 3 < 128) {
        const float* xp = xbase + (t + 3) * 32;
        xa1 = *(const float4*)xp;
        xb1 = *(const float4*)(xp + 4);
      }
      stepA(H0[1], H0[0], cxa, cxb);
    } else {
      stepB(H0[1], H1[1], H1[0]);
    }
    LDS_BARRIER();
  }
  // ---- pipeline iteration t=128 (parity 0): B step 127 only
  if (isB) stepB(H0[0], H1[0], H1[1]);

  // ---- fc: out[b] = sum_i h1[i]*fcw[i] + fcb   (group B holds h1(127))
  if (isB) {
    float partial = fw[0] * hs01[0] + fw[1] * hs01[1] + fw[2] * hs23[0] + fw[3] * hs23[1];
    partial += __shfl_down(partial, 16, 64);
    partial += __shfl_down(partial, 32, 64);
    if (lane < 16) red[wa][l15] = partial;
  }
  __syncthreads();
  if (tid < 8) out[b0 + tid] = red[0][tid] + red[1][tid] + red[2][tid] + red[3][tid] + fcb0;
}

extern "C" void kernel_launch(void* const* d_in, const int* in_sizes, int n_in,
                              void* d_out, int out_size, void* d_ws, size_t ws_size,
                              hipStream_t stream) {
  (void)in_sizes; (void)n_in; (void)out_size; (void)d_ws; (void)ws_size;
  const float* x    = (const float*)d_in[0];
  const float* Wih0 = (const float*)d_in[1];
  const float* Whh0 = (const float*)d_in[2];
  const float* bih0 = (const float*)d_in[3];
  const float* bhh0 = (const float*)d_in[4];
  const float* Wih1 = (const float*)d_in[5];
  const float* Whh1 = (const float*)d_in[6];
  const float* bih1 = (const float*)d_in[7];
  const float* bhh1 = (const float*)d_in[8];
  const float* fcw  = (const float*)d_in[9];
  const float* fcb  = (const float*)d_in[10];
  float* out = (float*)d_out;

  gru_fused<<<512, 512, 0, stream>>>(x, Wih0, Whh0, bih0, bhh0,
                                     Wih1, Whh1, bih1, bhh1, fcw, fcb, out);
}